// Round 14
// baseline (53.493 us; speedup 1.0000x reference)
//
#include <hip/hip_runtime.h>
#include <hip/hip_bf16.h>

#define BB 2
#define SS 1024
#define DD 256

typedef __attribute__((ext_vector_type(8))) short bf16x8;
typedef __attribute__((ext_vector_type(4))) float f32x4;

__device__ __forceinline__ unsigned short f2bf(float f) {
    __hip_bfloat16 h = __float2bfloat16(f);
    return *reinterpret_cast<unsigned short*>(&h);
}
__device__ __forceinline__ float bf2f(unsigned short u) {
    __hip_bfloat16 h;
    *reinterpret_cast<unsigned short*>(&h) = u;
    return __bfloat162float(h);
}
__device__ __forceinline__ bf16x8 cvt8(float4 f0, float4 f1) {
    bf16x8 o;
    o[0] = (short)f2bf(f0.x); o[1] = (short)f2bf(f0.y);
    o[2] = (short)f2bf(f0.z); o[3] = (short)f2bf(f0.w);
    o[4] = (short)f2bf(f1.x); o[5] = (short)f2bf(f1.y);
    o[6] = (short)f2bf(f1.z); o[7] = (short)f2bf(f1.w);
    return o;
}

// ---------------------------------------------------------------------------
// Kernel 0: one-pass fp32->bf16 conversion (byte-identical to round 8).
// ---------------------------------------------------------------------------
__global__ __launch_bounds__(256) void cvt_bf16(
    const float* __restrict__ x,
    const float* __restrict__ Wq, const float* __restrict__ Wk,
    const float* __restrict__ Wv, const float* __restrict__ Wo,
    unsigned short* __restrict__ xb,
    unsigned short* __restrict__ Wqb, unsigned short* __restrict__ Wkb,
    unsigned short* __restrict__ Wvb, unsigned short* __restrict__ Wob)
{
    const int u = blockIdx.x * 256 + threadIdx.x;
    const float* src;
    unsigned short* dst;
    int base;
    if (u < 65536)      { src = x;  dst = xb;  base = u; }
    else if (u < 73728) { src = Wq; dst = Wqb; base = u - 65536; }
    else if (u < 81920) { src = Wk; dst = Wkb; base = u - 73728; }
    else if (u < 90112) { src = Wv; dst = Wvb; base = u - 81920; }
    else                { src = Wo; dst = Wob; base = u - 90112; }
    const float4* s4 = (const float4*)src + (size_t)base * 2;
    *(bf16x8*)(dst + (size_t)base * 8) = cvt8(s4[0], s4[1]);
}

// ---------------------------------------------------------------------------
// Kernel 1: QKV projection via MFMA + REGISTER PREFETCH.
// All 32 W-frags (4cb x 8db) hoisted into registers BEFORE the MFMA chains
// so no MFMA waits on an L2 round-trip (R13 post-mortem: VGPR=68 showed the
// compiler serialized load->MFMA). Same MFMA order per accumulator ->
// bit-identical results. ~190 VGPR, fits launch_bounds(256,2).
// ---------------------------------------------------------------------------
__global__ __launch_bounds__(256, 2) void qkv_mfma(
    const unsigned short* __restrict__ xb,
    const unsigned short* __restrict__ Wqb, const float* __restrict__ bq,
    const unsigned short* __restrict__ Wkb, const float* __restrict__ bk,
    const unsigned short* __restrict__ Wvb, const float* __restrict__ bv,
    unsigned short* __restrict__ Qb, unsigned short* __restrict__ Kb,
    unsigned short* __restrict__ VB,
    float* __restrict__ qq, float* __restrict__ kk)
{
    __shared__ float red[4][16];
    const int t = threadIdx.x;
    const int w = t >> 6, l = t & 63, lr = l & 15, lc = l >> 4;
    const int mat = blockIdx.x % 3;
    const int tile = blockIdx.x / 3;
    const int r0 = tile * 16;
    const int b = r0 >> 10;
    const int s_in_base = r0 & (SS - 1);

    const unsigned short* W = (mat == 0) ? Wqb : (mat == 1) ? Wkb : Wvb;
    const float* bias       = (mat == 0) ? bq  : (mat == 1) ? bk  : bv;

    // A-frags
    bf16x8 af[8];
#pragma unroll
    for (int db = 0; db < 8; ++db)
        af[db] = *(const bf16x8*)(xb + (size_t)(r0 + lr) * DD + db * 32 + 8 * lc);

    // PREFETCH: all 32 B-frags up front (independent loads, pipelined)
    bf16x8 wf[4][8];
#pragma unroll
    for (int cb = 0; cb < 4; ++cb)
#pragma unroll
        for (int db = 0; db < 8; ++db)
            wf[cb][db] = *(const bf16x8*)(
                W + (size_t)(64 * w + 16 * cb + lr) * DD + db * 32 + 8 * lc);

    float nrm[4] = {0.f, 0.f, 0.f, 0.f};

#pragma unroll
    for (int cb = 0; cb < 4; ++cb) {
        const int jb = 64 * w + 16 * cb;
        f32x4 acc = {0.f, 0.f, 0.f, 0.f};
#pragma unroll
        for (int db = 0; db < 8; ++db)
            acc = __builtin_amdgcn_mfma_f32_16x16x32_bf16(af[db], wf[cb][db], acc, 0, 0, 0);
        const float bv_ = bias[jb + lr];
#pragma unroll
        for (int r = 0; r < 4; ++r) {
            const int srow = r0 + lc * 4 + r;
            const float v = acc[r] + bv_;
            const unsigned short h = f2bf(v);
            if (mat == 0) {
                Qb[(size_t)srow * DD + jb + lr] = h;
                const float hv = bf2f(h); nrm[r] += hv * hv;
            } else if (mat == 1) {
                Kb[(size_t)srow * DD + jb + lr] = h;
                const float hv = bf2f(h); nrm[r] += hv * hv;
            } else {
                const int s_in = s_in_base + lc * 4 + r;
                const int kb32 = s_in >> 5;
                const int kslot = (s_in >> 3) & 3;
                const int jj = s_in & 7;
                const int db16 = 4 * w + cb;
                const size_t off = ((size_t)((b * 32 + kb32) * 16 + db16) << 9)
                                 + ((kslot * 16 + lr) << 3) + jj;
                VB[off] = h;
            }
        }
    }

    if (mat < 2) {
#pragma unroll
        for (int r = 0; r < 4; ++r) {
            float n = nrm[r];
#pragma unroll
            for (int m = 1; m < 16; m <<= 1) n += __shfl_xor(n, m, 64);
            if (lr == 0) red[w][lc * 4 + r] = n;
        }
        __syncthreads();
        if (t < 16) {
            const float s = red[0][t] + red[1][t] + red[2][t] + red[3][t];
            if (mat == 0) qq[r0 + t] = s;
            else          kk[r0 + t] = s;
        }
    }
}

// ---------------------------------------------------------------------------
// Kernel 2: FUSED attention + out-proj (R13 structure) + REGISTER PREFETCH.
// Phase A: K-frags double-buffered across kbi. Phase B: VB-frags + P-frag
// double-buffered across ki. Phase C: all 16 Wo-frags hoisted.
// All buffer indices compile-time after full unroll (rule #20).
// MFMA order per accumulator unchanged -> bit-identical results.
// ---------------------------------------------------------------------------
__global__ __launch_bounds__(512, 2) void attn_out_mfma(
    const unsigned short* __restrict__ Qb, const unsigned short* __restrict__ Kb,
    const unsigned short* __restrict__ VB,
    const float* __restrict__ qq, const float* __restrict__ kk,
    const unsigned short* __restrict__ Wob, const float* __restrict__ bo,
    float* __restrict__ out)
{
    __shared__ __align__(16) unsigned short P_s[16 * 1024];  // 32 KB
    __shared__ float kk_s[SS];                               // 4 KB
    __shared__ float qq_s[16];
    __shared__ float es_red[8][16];
    __shared__ float inv_s[16];
    unsigned short* att_s = P_s;     // reuse after PV: [16][264] padded

    const int t = threadIdx.x;
    const int w = t >> 6, l = t & 63, lr = l & 15, lc = l >> 4;
    const int rowbase = blockIdx.x * 16;       // global row
    const int b = rowbase >> 10;

    kk_s[t] = kk[b * SS + t];
    kk_s[t + 512] = kk[b * SS + t + 512];
    if (t < 16) qq_s[t] = qq[rowbase + t];

    // Q A-frags
    bf16x8 qf[8];
#pragma unroll
    for (int db = 0; db < 8; ++db)
        qf[db] = *(const bf16x8*)(Qb + (size_t)(rowbase + lr) * DD + db * 32 + 8 * lc);

    __syncthreads();

    // ---- Phase A: QK^T + exp; wave w owns k-cols [128w, 128w+128) ----
    // K-frags double-buffered: load kbi+1 while MFMA-ing kbi.
    float psum[4] = {0.f, 0.f, 0.f, 0.f};
    bf16x8 kf[2][8];
#pragma unroll
    for (int db = 0; db < 8; ++db)
        kf[0][db] = *(const bf16x8*)(
            Kb + (size_t)(b * SS + 128 * w + lr) * DD + db * 32 + 8 * lc);

#pragma unroll
    for (int kbi = 0; kbi < 8; ++kbi) {
        const int kb = 128 * w + 16 * kbi;
        if (kbi < 7) {
#pragma unroll
            for (int db = 0; db < 8; ++db)
                kf[(kbi + 1) & 1][db] = *(const bf16x8*)(
                    Kb + (size_t)(b * SS + kb + 16 + lr) * DD + db * 32 + 8 * lc);
        }
        f32x4 acc = {0.f, 0.f, 0.f, 0.f};
#pragma unroll
        for (int db = 0; db < 8; ++db)
            acc = __builtin_amdgcn_mfma_f32_16x16x32_bf16(qf[db], kf[kbi & 1][db], acc, 0, 0, 0);
        const int kcol = kb + lr;
        const float kkv = kk_s[kcol];
#pragma unroll
        for (int r = 0; r < 4; ++r) {
            const int qi = lc * 4 + r;
            const float d2 = fmaxf(qq_s[qi] + kkv - 2.f * acc[r], 0.f);
            const float e = __expf(-sqrtf(d2) * 0.0625f);
            psum[r] += e;
            P_s[qi * 1024 + (kcol ^ ((qi & 7) << 3))] = f2bf(e);
        }
    }
    // per-row sums
#pragma unroll
    for (int r = 0; r < 4; ++r) {
        float s = psum[r];
#pragma unroll
        for (int m = 1; m < 16; m <<= 1) s += __shfl_xor(s, m, 64);
        if (lr == 0) es_red[w][lc * 4 + r] = s;
    }
    __syncthreads();    // publishes P_s + es_red
    if (t < 16) {
        float s = 0.f;
#pragma unroll
        for (int ww = 0; ww < 8; ++ww) s += es_red[ww][t];
        inv_s[t] = 1.f / s;
    }

    // ---- Phase B: PV; wave w owns d-cols [32w, 32w+32) ----
    // VB-frags + P-frag double-buffered across ki.
    f32x4 acc2[2];
#pragma unroll
    for (int i = 0; i < 2; ++i) acc2[i] = (f32x4){0.f, 0.f, 0.f, 0.f};

    bf16x8 vf[2][2], pf[2];
    {
        const size_t tb0 = ((size_t)((b * 32 + 0) * 16 + 2 * w) << 9) + l * 8;
        vf[0][0] = *(const bf16x8*)(VB + tb0);
        vf[0][1] = *(const bf16x8*)(VB + tb0 + 512);
        pf[0] = *(const bf16x8*)(P_s + lr * 1024 + ((0) ^ ((lr & 7) << 3)) + 8 * lc * 0);
        // note: ki=0 P address = lr*1024 + ((0*32 + 8*lc) ^ ((lr&7)<<3))
        pf[0] = *(const bf16x8*)(P_s + lr * 1024 + ((8 * lc) ^ ((lr & 7) << 3)));
    }
#pragma unroll
    for (int ki = 0; ki < 32; ++ki) {
        if (ki < 31) {
            const size_t tbn = ((size_t)((b * 32 + ki + 1) * 16 + 2 * w) << 9) + l * 8;
            vf[(ki + 1) & 1][0] = *(const bf16x8*)(VB + tbn);
            vf[(ki + 1) & 1][1] = *(const bf16x8*)(VB + tbn + 512);
            pf[(ki + 1) & 1] = *(const bf16x8*)(
                P_s + lr * 1024 + ((32 * (ki + 1) + 8 * lc) ^ ((lr & 7) << 3)));
        }
        acc2[0] = __builtin_amdgcn_mfma_f32_16x16x32_bf16(pf[ki & 1], vf[ki & 1][0], acc2[0], 0, 0, 0);
        acc2[1] = __builtin_amdgcn_mfma_f32_16x16x32_bf16(pf[ki & 1], vf[ki & 1][1], acc2[1], 0, 0, 0);
    }
    __syncthreads();    // all P_s reads done; inv_s visible

    // normalize + write att (bf16) to padded LDS [16][264]
#pragma unroll
    for (int dbi = 0; dbi < 2; ++dbi)
#pragma unroll
        for (int r = 0; r < 4; ++r) {
            const int qi = lc * 4 + r;
            att_s[qi * 264 + 32 * w + 16 * dbi + lr] =
                f2bf(acc2[dbi][r] * inv_s[qi]);
        }
    __syncthreads();

    // ---- Phase C: out-proj; wave w owns out-cols [32w, 32w+32) ----
    bf16x8 af[8];
#pragma unroll
    for (int db = 0; db < 8; ++db)
        af[db] = *(const bf16x8*)(att_s + lr * 264 + db * 32 + 8 * lc);

    // PREFETCH all 16 Wo-frags
    bf16x8 wof[2][8];
#pragma unroll
    for (int cb = 0; cb < 2; ++cb)
#pragma unroll
        for (int db = 0; db < 8; ++db)
            wof[cb][db] = *(const bf16x8*)(
                Wob + (size_t)(32 * w + 16 * cb + lr) * DD + db * 32 + 8 * lc);

#pragma unroll
    for (int cb = 0; cb < 2; ++cb) {
        const int jb = 32 * w + 16 * cb;
        f32x4 acc = {0.f, 0.f, 0.f, 0.f};
#pragma unroll
        for (int db = 0; db < 8; ++db)
            acc = __builtin_amdgcn_mfma_f32_16x16x32_bf16(af[db], wof[cb][db], acc, 0, 0, 0);
        const float bov = bo[jb + lr];
#pragma unroll
        for (int r = 0; r < 4; ++r)
            out[(size_t)(rowbase + lc * 4 + r) * DD + jb + lr] = acc[r] + bov;
    }
}

// ---------------------------------------------------------------------------
extern "C" void kernel_launch(void* const* d_in, const int* in_sizes, int n_in,
                              void* d_out, int out_size, void* d_ws, size_t ws_size,
                              hipStream_t stream) {
    const float* x  = (const float*)d_in[0];
    const float* Wq = (const float*)d_in[1];
    const float* bq = (const float*)d_in[2];
    const float* Wk = (const float*)d_in[3];
    const float* bk = (const float*)d_in[4];
    const float* Wv = (const float*)d_in[5];
    const float* bv = (const float*)d_in[6];
    const float* Wo = (const float*)d_in[7];
    const float* bo = (const float*)d_in[8];
    float* out = (float*)d_out;

    // ws layout (bf16): Qb | Kb | VB | xb | Wqb | Wkb | Wvb | Wob || qq | kk
    const size_t rows = (size_t)BB * SS;            // 2048
    unsigned short* Qb  = (unsigned short*)d_ws;
    unsigned short* Kb  = Qb + rows * DD;
    unsigned short* VB  = Kb + rows * DD;
    unsigned short* xb  = VB + rows * DD;
    unsigned short* Wqb = xb + rows * DD;
    unsigned short* Wkb = Wqb + (size_t)DD * DD;
    unsigned short* Wvb = Wkb + (size_t)DD * DD;
    unsigned short* Wob = Wvb + (size_t)DD * DD;
    float* qq    = (float*)(Wob + (size_t)DD * DD);
    float* kk    = qq + rows;

    cvt_bf16<<<384, 256, 0, stream>>>(x, Wq, Wk, Wv, Wo,
                                      xb, Wqb, Wkb, Wvb, Wob);
    qkv_mfma<<<(int)(rows / 16) * 3, 256, 0, stream>>>(
        xb, Wqb, bq, Wkb, bk, Wvb, bv, Qb, Kb, VB, qq, kk);
    attn_out_mfma<<<(int)(rows / 16), 512, 0, stream>>>(
        Qb, Kb, VB, qq, kk, Wob, bo, out);
}

// Round 15
// 50.651 us; speedup vs baseline: 1.0561x; 1.0561x over previous
//
#include <hip/hip_runtime.h>
#include <hip/hip_bf16.h>

#define BB 2
#define SS 1024
#define DD 256

typedef __attribute__((ext_vector_type(8))) short bf16x8;
typedef __attribute__((ext_vector_type(4))) float f32x4;

__device__ __forceinline__ unsigned short f2bf(float f) {
    __hip_bfloat16 h = __float2bfloat16(f);
    return *reinterpret_cast<unsigned short*>(&h);
}
__device__ __forceinline__ float bf2f(unsigned short u) {
    __hip_bfloat16 h;
    *reinterpret_cast<unsigned short*>(&h) = u;
    return __bfloat162float(h);
}
__device__ __forceinline__ bf16x8 cvt8(float4 f0, float4 f1) {
    bf16x8 o;
    o[0] = (short)f2bf(f0.x); o[1] = (short)f2bf(f0.y);
    o[2] = (short)f2bf(f0.z); o[3] = (short)f2bf(f0.w);
    o[4] = (short)f2bf(f1.x); o[5] = (short)f2bf(f1.y);
    o[6] = (short)f2bf(f1.z); o[7] = (short)f2bf(f1.w);
    return o;
}

// ---------------------------------------------------------------------------
// Kernel 0: one-pass fp32->bf16 conversion (byte-identical to round 8).
// ---------------------------------------------------------------------------
__global__ __launch_bounds__(256) void cvt_bf16(
    const float* __restrict__ x,
    const float* __restrict__ Wq, const float* __restrict__ Wk,
    const float* __restrict__ Wv, const float* __restrict__ Wo,
    unsigned short* __restrict__ xb,
    unsigned short* __restrict__ Wqb, unsigned short* __restrict__ Wkb,
    unsigned short* __restrict__ Wvb, unsigned short* __restrict__ Wob)
{
    const int u = blockIdx.x * 256 + threadIdx.x;
    const float* src;
    unsigned short* dst;
    int base;
    if (u < 65536)      { src = x;  dst = xb;  base = u; }
    else if (u < 73728) { src = Wq; dst = Wqb; base = u - 65536; }
    else if (u < 81920) { src = Wk; dst = Wkb; base = u - 73728; }
    else if (u < 90112) { src = Wv; dst = Wvb; base = u - 81920; }
    else                { src = Wo; dst = Wob; base = u - 90112; }
    const float4* s4 = (const float4*)src + (size_t)base * 2;
    *(bf16x8*)(dst + (size_t)base * 8) = cvt8(s4[0], s4[1]);
}

// ---------------------------------------------------------------------------
// Kernel 1: QKV projection via MFMA, COLUMN-SPLIT x2.
// grid = 128 tiles x 3 mats x 2 col-halves = 768 blocks (3 blocks/CU).
// Block = 16 rows x 128 cols; wave w owns 32 cols (2 cb x 16).
// Per-wave serial path halved vs R13 (2 MFMA chains instead of 4).
// Row norms are PARTIAL per col-half: qq/kk laid out as [2][rows]; the attn
// kernel sums the two halves at load time.
// ---------------------------------------------------------------------------
__global__ __launch_bounds__(256, 2) void qkv_mfma(
    const unsigned short* __restrict__ xb,
    const unsigned short* __restrict__ Wqb, const float* __restrict__ bq,
    const unsigned short* __restrict__ Wkb, const float* __restrict__ bk,
    const unsigned short* __restrict__ Wvb, const float* __restrict__ bv,
    unsigned short* __restrict__ Qb, unsigned short* __restrict__ Kb,
    unsigned short* __restrict__ VB,
    float* __restrict__ qq, float* __restrict__ kk)   // [2][BB*SS] partials
{
    __shared__ float red[4][16];
    const int t = threadIdx.x;
    const int w = t >> 6, l = t & 63, lr = l & 15, lc = l >> 4;
    const int bx = blockIdx.x;
    const int mat = bx % 3;
    const int rest = bx / 3;
    const int tile = rest >> 1;
    const int ch = rest & 1;                 // column half
    const int r0 = tile * 16;
    const int b = r0 >> 10;
    const int s_in_base = r0 & (SS - 1);
    const size_t rows = (size_t)BB * SS;

    const unsigned short* W = (mat == 0) ? Wqb : (mat == 1) ? Wkb : Wvb;
    const float* bias       = (mat == 0) ? bq  : (mat == 1) ? bk  : bv;

    // A-frags
    bf16x8 af[8];
#pragma unroll
    for (int db = 0; db < 8; ++db)
        af[db] = *(const bf16x8*)(xb + (size_t)(r0 + lr) * DD + db * 32 + 8 * lc);

    float nrm[4] = {0.f, 0.f, 0.f, 0.f};

#pragma unroll
    for (int cb = 0; cb < 2; ++cb) {
        const int jb = 128 * ch + 32 * w + 16 * cb;
        f32x4 acc = {0.f, 0.f, 0.f, 0.f};
#pragma unroll
        for (int db = 0; db < 8; ++db) {
            bf16x8 bf = *(const bf16x8*)(W + (size_t)(jb + lr) * DD + db * 32 + 8 * lc);
            acc = __builtin_amdgcn_mfma_f32_16x16x32_bf16(af[db], bf, acc, 0, 0, 0);
        }
        const float bv_ = bias[jb + lr];
#pragma unroll
        for (int r = 0; r < 4; ++r) {
            const int srow = r0 + lc * 4 + r;     // C/D: row=(l>>4)*4+r, col=l%16
            const float v = acc[r] + bv_;
            const unsigned short h = f2bf(v);
            if (mat == 0) {
                Qb[(size_t)srow * DD + jb + lr] = h;
                const float hv = bf2f(h); nrm[r] += hv * hv;
            } else if (mat == 1) {
                Kb[(size_t)srow * DD + jb + lr] = h;
                const float hv = bf2f(h); nrm[r] += hv * hv;
            } else {
                // VB layout: tile(b, kb32=s/32, db16=d/16) of 1024B
                const int s_in = s_in_base + lc * 4 + r;
                const int kb32 = s_in >> 5;
                const int kslot = (s_in >> 3) & 3;
                const int jj = s_in & 7;
                const int db16 = ch * 8 + 2 * w + cb;
                const size_t off = ((size_t)((b * 32 + kb32) * 16 + db16) << 9)
                                 + ((kslot * 16 + lr) << 3) + jj;
                VB[off] = h;
            }
        }
    }

    if (mat < 2) {
#pragma unroll
        for (int r = 0; r < 4; ++r) {
            float n = nrm[r];
#pragma unroll
            for (int m = 1; m < 16; m <<= 1) n += __shfl_xor(n, m, 64);
            if (lr == 0) red[w][lc * 4 + r] = n;
        }
        __syncthreads();
        if (t < 16) {
            const float s = red[0][t] + red[1][t] + red[2][t] + red[3][t];
            if (mat == 0) qq[(size_t)ch * rows + r0 + t] = s;
            else          kk[(size_t)ch * rows + r0 + t] = s;
        }
    }
}

// ---------------------------------------------------------------------------
// Kernel 2: FUSED attention + output projection (byte-identical to R13
// except qq/kk loads sum the two column-half partials).
// grid = 128 blocks, 512 threads (8 waves).
// ---------------------------------------------------------------------------
__global__ __launch_bounds__(512, 2) void attn_out_mfma(
    const unsigned short* __restrict__ Qb, const unsigned short* __restrict__ Kb,
    const unsigned short* __restrict__ VB,
    const float* __restrict__ qq, const float* __restrict__ kk,  // [2][rows]
    const unsigned short* __restrict__ Wob, const float* __restrict__ bo,
    float* __restrict__ out)
{
    __shared__ __align__(16) unsigned short P_s[16 * 1024];  // 32 KB
    __shared__ float kk_s[SS];                               // 4 KB
    __shared__ float qq_s[16];
    __shared__ float es_red[8][16];
    __shared__ float inv_s[16];
    unsigned short* att_s = P_s;     // reuse after PV: [16][264] padded

    const int t = threadIdx.x;
    const int w = t >> 6, l = t & 63, lr = l & 15, lc = l >> 4;
    const int rowbase = blockIdx.x * 16;       // global row
    const int b = rowbase >> 10;
    const size_t rows = (size_t)BB * SS;

    kk_s[t]       = kk[b * SS + t]       + kk[rows + b * SS + t];
    kk_s[t + 512] = kk[b * SS + t + 512] + kk[rows + b * SS + t + 512];
    if (t < 16) qq_s[t] = qq[rowbase + t] + qq[rows + rowbase + t];

    // Q A-frags
    bf16x8 qf[8];
#pragma unroll
    for (int db = 0; db < 8; ++db)
        qf[db] = *(const bf16x8*)(Qb + (size_t)(rowbase + lr) * DD + db * 32 + 8 * lc);

    __syncthreads();

    // ---- Phase A: QK^T + exp; wave w owns k-cols [128w, 128w+128) ----
    float psum[4] = {0.f, 0.f, 0.f, 0.f};
#pragma unroll
    for (int kbi = 0; kbi < 8; ++kbi) {
        const int kb = 128 * w + 16 * kbi;
        f32x4 acc = {0.f, 0.f, 0.f, 0.f};
#pragma unroll
        for (int db = 0; db < 8; ++db) {
            bf16x8 kf = *(const bf16x8*)(
                Kb + (size_t)(b * SS + kb + lr) * DD + db * 32 + 8 * lc);
            acc = __builtin_amdgcn_mfma_f32_16x16x32_bf16(qf[db], kf, acc, 0, 0, 0);
        }
        const int kcol = kb + lr;
        const float kkv = kk_s[kcol];
#pragma unroll
        for (int r = 0; r < 4; ++r) {
            const int qi = lc * 4 + r;
            const float d2 = fmaxf(qq_s[qi] + kkv - 2.f * acc[r], 0.f);
            const float e = __expf(-sqrtf(d2) * 0.0625f);
            psum[r] += e;
            P_s[qi * 1024 + (kcol ^ ((qi & 7) << 3))] = f2bf(e);
        }
    }
    // per-row sums: reduce across lr (16), then across 8 waves via LDS
#pragma unroll
    for (int r = 0; r < 4; ++r) {
        float s = psum[r];
#pragma unroll
        for (int m = 1; m < 16; m <<= 1) s += __shfl_xor(s, m, 64);
        if (lr == 0) es_red[w][lc * 4 + r] = s;
    }
    __syncthreads();    // publishes P_s + es_red
    if (t < 16) {
        float s = 0.f;
#pragma unroll
        for (int ww = 0; ww < 8; ++ww) s += es_red[ww][t];
        inv_s[t] = 1.f / s;
    }

    // ---- Phase B: PV; wave w owns d-cols [32w, 32w+32) ----
    f32x4 acc2[2];
#pragma unroll
    for (int i = 0; i < 2; ++i) acc2[i] = (f32x4){0.f, 0.f, 0.f, 0.f};

#pragma unroll
    for (int ki = 0; ki < 32; ++ki) {
        bf16x8 pf = *(const bf16x8*)(
            P_s + lr * 1024 + ((32 * ki + 8 * lc) ^ ((lr & 7) << 3)));
        const size_t tbase =
            ((size_t)((b * 32 + ki) * 16 + 2 * w) << 9) + l * 8;
#pragma unroll
        for (int dbi = 0; dbi < 2; ++dbi) {
            bf16x8 vf = *(const bf16x8*)(VB + tbase + ((size_t)dbi << 9));
            acc2[dbi] = __builtin_amdgcn_mfma_f32_16x16x32_bf16(pf, vf, acc2[dbi], 0, 0, 0);
        }
    }
    __syncthreads();    // all P_s reads done; inv_s visible

    // normalize + write att (bf16) to padded LDS [16][264]
#pragma unroll
    for (int dbi = 0; dbi < 2; ++dbi)
#pragma unroll
        for (int r = 0; r < 4; ++r) {
            const int qi = lc * 4 + r;
            att_s[qi * 264 + 32 * w + 16 * dbi + lr] =
                f2bf(acc2[dbi][r] * inv_s[qi]);
        }
    __syncthreads();

    // ---- Phase C: out-proj; wave w owns out-cols [32w, 32w+32) ----
    bf16x8 af[8];
#pragma unroll
    for (int db = 0; db < 8; ++db)
        af[db] = *(const bf16x8*)(att_s + lr * 264 + db * 32 + 8 * lc);

#pragma unroll
    for (int cb = 0; cb < 2; ++cb) {
        const int jb = 32 * w + 16 * cb;
        f32x4 acc = {0.f, 0.f, 0.f, 0.f};
#pragma unroll
        for (int db = 0; db < 8; ++db) {
            bf16x8 bf = *(const bf16x8*)(Wob + (size_t)(jb + lr) * DD + db * 32 + 8 * lc);
            acc = __builtin_amdgcn_mfma_f32_16x16x32_bf16(af[db], bf, acc, 0, 0, 0);
        }
        const float bov = bo[jb + lr];
#pragma unroll
        for (int r = 0; r < 4; ++r)
            out[(size_t)(rowbase + lc * 4 + r) * DD + jb + lr] = acc[r] + bov;
    }
}

// ---------------------------------------------------------------------------
extern "C" void kernel_launch(void* const* d_in, const int* in_sizes, int n_in,
                              void* d_out, int out_size, void* d_ws, size_t ws_size,
                              hipStream_t stream) {
    const float* x  = (const float*)d_in[0];
    const float* Wq = (const float*)d_in[1];
    const float* bq = (const float*)d_in[2];
    const float* Wk = (const float*)d_in[3];
    const float* bk = (const float*)d_in[4];
    const float* Wv = (const float*)d_in[5];
    const float* bv = (const float*)d_in[6];
    const float* Wo = (const float*)d_in[7];
    const float* bo = (const float*)d_in[8];
    float* out = (float*)d_out;

    // ws layout (bf16): Qb | Kb | VB | xb | Wqb | Wkb | Wvb | Wob ||
    //                   qq[2][rows] | kk[2][rows]  (fp32 partials)
    const size_t rows = (size_t)BB * SS;            // 2048
    unsigned short* Qb  = (unsigned short*)d_ws;
    unsigned short* Kb  = Qb + rows * DD;
    unsigned short* VB  = Kb + rows * DD;
    unsigned short* xb  = VB + rows * DD;
    unsigned short* Wqb = xb + rows * DD;
    unsigned short* Wkb = Wqb + (size_t)DD * DD;
    unsigned short* Wvb = Wkb + (size_t)DD * DD;
    unsigned short* Wob = Wvb + (size_t)DD * DD;
    float* qq    = (float*)(Wob + (size_t)DD * DD);  // 2*rows
    float* kk    = qq + 2 * rows;                    // 2*rows

    cvt_bf16<<<384, 256, 0, stream>>>(x, Wq, Wk, Wv, Wo,
                                      xb, Wqb, Wkb, Wvb, Wob);
    qkv_mfma<<<768, 256, 0, stream>>>(
        xb, Wqb, bq, Wkb, bk, Wvb, bv, Qb, Kb, VB, qq, kk);
    attn_out_mfma<<<(int)(rows / 16), 512, 0, stream>>>(
        Qb, Kb, VB, qq, kk, Wob, bo, out);
}